// Round 13
// baseline (258.030 us; speedup 1.0000x reference)
//
#include <hip/hip_runtime.h>
#include <hip/hip_bf16.h>
#include <cstdint>

// ---------------- problem constants ----------------
#define BSZ   4
#define TSEQ  2048
#define DMOD  768
#define DCONV 384
#define DGRIF 384
#define DFFN  2048
#define BT    (BSZ*TSEQ)          // 8192
#define NG1   1920                // 2*DCONV + 3*DGRIF
#define EPS_  1e-6f

typedef __bf16 bf16;
typedef __bf16 bf16x8 __attribute__((ext_vector_type(8)));
typedef float  f32x4  __attribute__((ext_vector_type(4)));

__device__ __forceinline__ float sigmoidf_(float x) { return 1.f / (1.f + __expf(-x)); }

__device__ __forceinline__ void gload_lds16(const void* g, void* l) {
  __builtin_amdgcn_global_load_lds(
      (const __attribute__((address_space(1))) void*)(uintptr_t)g,
      (__attribute__((address_space(3))) void*)(uint32_t)(uintptr_t)l,
      16, 0, 0);
}

// bijective XCD swizzle: all GEMM grids are % 8 == 0
__device__ __forceinline__ int swz_wg() {
  const int nwg = gridDim.x;
  const int bid = blockIdx.x;
  const int cpx = nwg >> 3;
  return (bid & 7) * cpx + (bid >> 3);
}

// ---------------- prep: merged weight transposes + pre-rmsnorm (1 launch) ----------------
__global__ __launch_bounds__(256) void prep_kernel(
    const float* __restrict__ conv_in_w, const float* __restrict__ gv,
    const float* __restrict__ gr, const float* __restrict__ gi,
    const float* __restrict__ out_w, const float* __restrict__ w1,
    const float* __restrict__ w3, const float* __restrict__ w2,
    bf16* __restrict__ WT_G1, bf16* __restrict__ WT_OUT,
    bf16* __restrict__ WT_W13, bf16* __restrict__ WT_W2,
    const float* __restrict__ x, const float* __restrict__ pre_w,
    bf16* __restrict__ XN)
{
  __shared__ float tile[32][33];
  if (blockIdx.x >= 6624) {
    // ---- rmsnorm branch ----
    const int row = blockIdx.x - 6624;
    const int tid = threadIdx.x;
    const float* xr = x + (size_t)row * DMOD;
    float v0 = xr[tid], v1 = xr[tid + 256], v2 = xr[tid + 512];
    float s = v0*v0 + v1*v1 + v2*v2;
    #pragma unroll
    for (int o = 32; o > 0; o >>= 1) s += __shfl_down(s, o, 64);
    __shared__ float sbuf[4];
    if ((tid & 63) == 0) sbuf[tid >> 6] = s;
    __syncthreads();
    float tot = sbuf[0] + sbuf[1] + sbuf[2] + sbuf[3];
    float rms = rsqrtf(tot * (1.f / (float)DMOD) + EPS_);
    bf16* orow = XN + (size_t)row * DMOD;
    orow[tid]       = (bf16)(v0 * rms * pre_w[tid]);
    orow[tid + 256] = (bf16)(v1 * rms * pre_w[tid + 256]);
    orow[tid + 512] = (bf16)(v2 * rms * pre_w[tid + 512]);
    return;
  }
  // ---- transpose branch ----
  int t = blockIdx.x;
  const float* W; bf16* Wt; int R, C, mode = 0, half = 0;
  if      (t < 576)  {           W = conv_in_w; Wt = WT_G1;                        R = 768;  C = 768; }
  else if (t < 864)  { t -= 576;  W = gv;  Wt = WT_G1 + (size_t)768  * DMOD;       R = 768;  C = 384; }
  else if (t < 1152) { t -= 864;  W = gr;  Wt = WT_G1 + (size_t)1152 * DMOD;       R = 768;  C = 384; }
  else if (t < 1440) { t -= 1152; W = gi;  Wt = WT_G1 + (size_t)1536 * DMOD;       R = 768;  C = 384; }
  else if (t < 2016) { t -= 1440; W = out_w; Wt = WT_OUT;                          R = 768;  C = 768; }
  else if (t < 3552) { t -= 2016; W = w1;  Wt = WT_W13; mode = 1; half = 0;        R = 768;  C = 2048; }
  else if (t < 5088) { t -= 3552; W = w3;  Wt = WT_W13; mode = 1; half = 64;       R = 768;  C = 2048; }
  else               { t -= 5088; W = w2;  Wt = WT_W2;                             R = 2048; C = 768; }

  const int xt = C >> 5;
  const int tc = (t % xt) * 32, tr = (t / xt) * 32;
  const int lx = threadIdx.x & 31;
  const int ly = threadIdx.x >> 5;
  #pragma unroll
  for (int i = ly; i < 32; i += 8) {
    int r = tr + i, c = tc + lx;
    tile[i][lx] = (r < R && c < C) ? W[(size_t)r * C + c] : 0.f;
  }
  __syncthreads();
  #pragma unroll
  for (int i = ly; i < 32; i += 8) {
    int oc = tc + i;
    int orr = tr + lx;
    if (oc < C && orr < R) {
      int orow = (mode == 0) ? oc : ((oc >> 6) << 7) + half + (oc & 63);
      Wt[(size_t)orow * R + orr] = (bf16)tile[lx][i];
    }
  }
}

// ---------------- rmsnorm (x fp32 -> out bf16) ----------------
__global__ __launch_bounds__(256) void rmsnorm_kernel(
    const float* __restrict__ x, const float* __restrict__ w, bf16* __restrict__ out)
{
  __shared__ float sbuf[4];
  const int row = blockIdx.x;
  const int tid = threadIdx.x;
  const float* xr = x + (size_t)row * DMOD;
  float v0 = xr[tid], v1 = xr[tid + 256], v2 = xr[tid + 512];
  float s = v0*v0 + v1*v1 + v2*v2;
  #pragma unroll
  for (int o = 32; o > 0; o >>= 1) s += __shfl_down(s, o, 64);
  if ((tid & 63) == 0) sbuf[tid >> 6] = s;
  __syncthreads();
  float tot = sbuf[0] + sbuf[1] + sbuf[2] + sbuf[3];
  float rms = rsqrtf(tot * (1.f / (float)DMOD) + EPS_);
  bf16* orow = out + (size_t)row * DMOD;
  orow[tid]       = (bf16)(v0 * rms * w[tid]);
  orow[tid + 256] = (bf16)(v1 * rms * w[tid + 256]);
  orow[tid + 512] = (bf16)(v2 * rms * w[tid + 512]);
}

// ---------------- 128x128 GEMM, dbuf minimum-2-phase, T2-swizzled (GEMM1) ----------------
__global__ __launch_bounds__(256) void gemm_w128d(
    const bf16* __restrict__ A, const bf16* __restrict__ Bt, bf16* __restrict__ C,
    int M, int N, int K, int nx)
{
  __shared__ alignas(16) unsigned short As[2][128 * 64];   // 2 x 16 KB
  __shared__ alignas(16) unsigned short Bs[2][128 * 64];   // 2 x 16 KB

  const int wg = swz_wg();
  const int m0 = (wg / nx) * 128, n0 = (wg % nx) * 128;
  const int tid  = threadIdx.x;
  const int wave = tid >> 6;
  const int lane = tid & 63;
  const int wr = wave >> 1, wc = wave & 1;

  f32x4 acc[4][4] = {};
  const int srow = lane >> 3;
  const int scol = ((lane & 7) ^ srow) * 8;
  const int lr = lane & 15;
  const int lsw = lr & 7;
  const int lk4 = lane >> 4;

  auto stage = [&](int buf, int k0) {
    #pragma unroll
    for (int it = 0; it < 4; ++it) {
      const int chunk = wave * 4 + it;
      const int row = chunk * 8 + srow;
      gload_lds16(A  + (size_t)(m0 + row) * K + k0 + scol, (char*)As[buf] + chunk * 1024);
      gload_lds16(Bt + (size_t)(n0 + row) * K + k0 + scol, (char*)Bs[buf] + chunk * 1024);
    }
  };

  stage(0, 0);
  __syncthreads();

  int cur = 0;
  for (int k0 = 0; k0 < K; k0 += 64) {
    if (k0 + 64 < K) stage(cur ^ 1, k0 + 64);
    #pragma unroll
    for (int kk = 0; kk < 2; ++kk) {
      bf16x8 af[4], bfr[4];
      #pragma unroll
      for (int i = 0; i < 4; ++i)
        af[i] = *reinterpret_cast<const bf16x8*>(
            &As[cur][(wr*64 + i*16 + lr) * 64 + (((kk*4 + lk4) ^ lsw) * 8)]);
      #pragma unroll
      for (int i = 0; i < 4; ++i)
        bfr[i] = *reinterpret_cast<const bf16x8*>(
            &Bs[cur][(wc*64 + i*16 + lr) * 64 + (((kk*4 + lk4) ^ lsw) * 8)]);
      #pragma unroll
      for (int mi = 0; mi < 4; ++mi)
        #pragma unroll
        for (int ni = 0; ni < 4; ++ni)
          acc[mi][ni] = __builtin_amdgcn_mfma_f32_16x16x32_bf16(af[mi], bfr[ni], acc[mi][ni], 0, 0, 0);
    }
    __syncthreads();
    cur ^= 1;
  }

  #pragma unroll
  for (int mi = 0; mi < 4; ++mi)
    #pragma unroll
    for (int ni = 0; ni < 4; ++ni)
      #pragma unroll
      for (int reg = 0; reg < 4; ++reg) {
        const int r = m0 + wr*64 + mi*16 + lk4 * 4 + reg;
        const int c = n0 + wc*64 + ni*16 + lr;
        C[(size_t)r * N + c] = (bf16)acc[mi][ni][reg];
      }
}

// ---------------- fused FFN GEMM: 256x128 tile, 512 thr, 2D XCD chunking (proven 76.9 us) ----------------
// Grid 1024 = 32 m-tiles x 32 n-blocks. XCD k = (m-group k&3: 8 m-tiles) x (n-half k>>2: 16 n-blocks).
__global__ __launch_bounds__(512) void gemm_ffn13b(
    const bf16* __restrict__ A, const bf16* __restrict__ Bt, bf16* __restrict__ H,
    int M, int K)
{
  __shared__ alignas(16) unsigned short As[256 * 64];   // 32 KB
  __shared__ alignas(16) unsigned short Bs[128 * 64];   // 16 KB
  bf16* comb = reinterpret_cast<bf16*>(As);

  const int xcd = blockIdx.x & 7;
  const int w   = blockIdx.x >> 3;            // 0..127
  const int mt  = (xcd & 3) * 8 + (w >> 4);   // m-tile 0..31
  const int bx  = (xcd >> 2) * 16 + (w & 15); // n-block 0..31
  const int m0 = mt * 256;
  const int n0 = bx * 128;
  const int tid  = threadIdx.x;
  const int wave = tid >> 6;
  const int lane = tid & 63;
  const int wr = wave >> 1;      // 0..3
  const int wc = wave & 1;       // 0..1
  const int lr = lane & 15;
  const int lk4 = lane >> 4;

  f32x4 acc[4][4] = {};

  for (int k0 = 0; k0 < K; k0 += 64) {
    __syncthreads();
    #pragma unroll
    for (int p = 0; p < 4; ++p) {       // A: 256 rows x 64 cols
      const int f = (p << 9) + tid;
      const int row = f >> 3;
      const int gs = (f & 7) ^ (row & 7);
      gload_lds16(A + (size_t)(m0 + row) * K + k0 + gs * 8,
                  (char*)As + (p << 13) + (wave << 10));
    }
    #pragma unroll
    for (int p = 0; p < 2; ++p) {       // B: 128 rows
      const int f = (p << 9) + tid;
      const int row = f >> 3;
      const int gs = (f & 7) ^ (row & 7);
      gload_lds16(Bt + (size_t)(n0 + row) * K + k0 + gs * 8,
                  (char*)Bs + (p << 13) + (wave << 10));
    }
    __syncthreads();
    #pragma unroll
    for (int kk = 0; kk < 2; ++kk) {
      bf16x8 af[4], bfr[4];
      #pragma unroll
      for (int i = 0; i < 4; ++i) {
        const int r = wr*64 + i*16 + lr;
        af[i] = *reinterpret_cast<const bf16x8*>(&As[r * 64 + (((kk*4 + lk4) ^ (r & 7)) * 8)]);
      }
      #pragma unroll
      for (int i = 0; i < 4; ++i) {
        const int r = wc*64 + i*16 + lr;
        bfr[i] = *reinterpret_cast<const bf16x8*>(&Bs[r * 64 + (((kk*4 + lk4) ^ (r & 7)) * 8)]);
      }
      #pragma unroll
      for (int mi = 0; mi < 4; ++mi)
        #pragma unroll
        for (int ni = 0; ni < 4; ++ni)
          acc[mi][ni] = __builtin_amdgcn_mfma_f32_16x16x32_bf16(af[mi], bfr[ni], acc[mi][ni], 0, 0, 0);
    }
  }

  __syncthreads();   // As dead; reuse as comb
  if (wc == 1) {
    #pragma unroll
    for (int mi = 0; mi < 4; ++mi)
      #pragma unroll
      for (int ni = 0; ni < 4; ++ni)
        #pragma unroll
        for (int reg = 0; reg < 4; ++reg) {
          const int row = wr*64 + mi*16 + lk4 * 4 + reg;
          const int col = ni*16 + lr;
          comb[row * 64 + col] = (bf16)acc[mi][ni][reg];
        }
  }
  __syncthreads();
  if (wc == 0) {
    #pragma unroll
    for (int mi = 0; mi < 4; ++mi)
      #pragma unroll
      for (int ni = 0; ni < 4; ++ni)
        #pragma unroll
        for (int reg = 0; reg < 4; ++reg) {
          const int row = wr*64 + mi*16 + lk4 * 4 + reg;
          const int col = ni*16 + lr;
          float p3 = (float)comb[row * 64 + col];
          float p1 = acc[mi][ni][reg];
          H[(size_t)(m0 + row) * DFFN + bx * 64 + col] = (bf16)(p1 * sigmoidf_(p1) * p3);
        }
  }
}

// ---------------- narrow GEMM: 128x64 tile, dbuf minimum-2-phase ----------------
// EPI 0: momentum epilogue.  EPI 1: Cf += acc.
template <int EPI>
__global__ __launch_bounds__(256) void gemm_n64(
    const bf16* __restrict__ A, const bf16* __restrict__ Bt, float* __restrict__ C,
    const float* __restrict__ xin, const float* __restrict__ vin,
    float* __restrict__ outv, const float* __restrict__ log_beta,
    int M, int N, int K, int nx)
{
  __shared__ alignas(16) unsigned short As[2][128 * 64];   // 2 x 16 KB
  __shared__ alignas(16) unsigned short Bs[2][64 * 64];    // 2 x  8 KB

  const int wg = swz_wg();
  const int m0 = (wg / nx) * 128, n0 = (wg % nx) * 64;
  const int tid  = threadIdx.x;
  const int wave = tid >> 6;
  const int lane = tid & 63;
  const int wr = wave >> 1, wc = wave & 1;

  f32x4 acc[4][2] = {};
  const int srow = lane >> 3;
  const int scol = ((lane & 7) ^ srow) * 8;
  const int lr = lane & 15;
  const int lsw = lr & 7;
  const int lk4 = lane >> 4;

  auto stage = [&](int buf, int k0) {
    #pragma unroll
    for (int it = 0; it < 6; ++it) {
      const int chunk = wave * 6 + it;
      if (chunk < 16) {
        const int row = chunk * 8 + srow;
        gload_lds16(A + (size_t)(m0 + row) * K + k0 + scol,
                    (char*)As[buf] + chunk * 1024);
      } else {
        const int row = (chunk - 16) * 8 + srow;
        gload_lds16(Bt + (size_t)(n0 + row) * K + k0 + scol,
                    (char*)Bs[buf] + (chunk - 16) * 1024);
      }
    }
  };

  stage(0, 0);
  __syncthreads();

  int cur = 0;
  for (int k0 = 0; k0 < K; k0 += 64) {
    if (k0 + 64 < K) stage(cur ^ 1, k0 + 64);
    #pragma unroll
    for (int kk = 0; kk < 2; ++kk) {
      bf16x8 af[4], bfr[2];
      #pragma unroll
      for (int i = 0; i < 4; ++i)
        af[i] = *reinterpret_cast<const bf16x8*>(
            &As[cur][(wr*64 + i*16 + lr) * 64 + (((kk*4 + lk4) ^ lsw) * 8)]);
      #pragma unroll
      for (int i = 0; i < 2; ++i)
        bfr[i] = *reinterpret_cast<const bf16x8*>(
            &Bs[cur][(wc*32 + i*16 + lr) * 64 + (((kk*4 + lk4) ^ lsw) * 8)]);
      #pragma unroll
      for (int mi = 0; mi < 4; ++mi)
        #pragma unroll
        for (int ni = 0; ni < 2; ++ni)
          acc[mi][ni] = __builtin_amdgcn_mfma_f32_16x16x32_bf16(af[mi], bfr[ni], acc[mi][ni], 0, 0, 0);
    }
    __syncthreads();
    cur ^= 1;
  }

  const float beta = (EPI == 0) ? sigmoidf_(log_beta[0]) : 0.f;
  #pragma unroll
  for (int mi = 0; mi < 4; ++mi)
    #pragma unroll
    for (int ni = 0; ni < 2; ++ni)
      #pragma unroll
      for (int reg = 0; reg < 4; ++reg) {
        const int r = m0 + wr*64 + mi*16 + lk4 * 4 + reg;
        const int c = n0 + wc*32 + ni*16 + lr;
        const size_t off = (size_t)r * N + c;
        float v = acc[mi][ni][reg];
        if (EPI == 0) {
          float vel = beta * vin[off] + v;
          float x1  = xin[off] + vel;
          outv[off] = vel;
          C[off] = x1;
        } else {
          C[off] += v;
        }
      }
}

// ---------------- RG-LRU 2-pass chunked scan + fused conv ----------------
#define NCH  32
#define CLEN 64

__device__ __forceinline__ void lru_step(const bf16* row, int c, float coef,
                                         float& a, float& g)
{
  float v  = (float)row[2*DCONV + c];
  float r  = sigmoidf_((float)row[2*DCONV + DGRIF + c]);
  float is = sigmoidf_((float)row[2*DCONV + 2*DGRIF + c]);
  float la = coef * r;
  a = __expf(la);
  g = sqrtf(fmaxf(1.f - __expf(2.f * la), EPS_)) * (is * v);
}

__global__ __launch_bounds__(256) void lru_pass1(
    const bf16* __restrict__ g1, const float* __restrict__ lam,
    float* __restrict__ cA, float* __restrict__ cB)
{
  const int idx = blockIdx.x * 256 + threadIdx.x;
  const int c = idx % DGRIF;
  const int rest = idx / DGRIF;
  const int j = rest & (NCH - 1);
  const int b = rest / NCH;
  const float coef = -8.f * log1pf(__expf(lam[c]));
  const bf16* base = g1 + (size_t)(b * TSEQ + j * CLEN) * NG1;
  float A = 1.f, Bv = 0.f;
  #pragma unroll 4
  for (int t = 0; t < CLEN; ++t) {
    float a, g;
    lru_step(base + (size_t)t * NG1, c, coef, a, g);
    A *= a;
    Bv = a * Bv + g;
  }
  cA[((size_t)b * DGRIF + c) * NCH + j] = A;
  cB[((size_t)b * DGRIF + c) * NCH + j] = Bv;
}

__global__ __launch_bounds__(256) void lru_pass2(
    const bf16* __restrict__ g1, const float* __restrict__ lam,
    const float* __restrict__ cA, const float* __restrict__ cB,
    const float* __restrict__ dw, bf16* __restrict__ mixin)
{
  const int idx = blockIdx.x * 256 + threadIdx.x;
  const int c = idx % DGRIF;
  const int rest = idx / DGRIF;
  const int j = rest & (NCH - 1);
  const int b = rest / NCH;
  const float coef = -8.f * log1pf(__expf(lam[c]));
  float Hc = 0.f;
  const float* pa = cA + ((size_t)b * DGRIF + c) * NCH;
  const float* pb = cB + ((size_t)b * DGRIF + c) * NCH;
  for (int k = 0; k < j; ++k) Hc = pa[k] * Hc + pb[k];

  const int t0 = j * CLEN;
  const bf16* base = g1 + (size_t)(b * TSEQ + t0) * NG1;
  const float w0 = dw[c*3], w1 = dw[c*3 + 1], w2 = dw[c*3 + 2];
  float u1 = (t0 >= 1) ? (float)base[-(ptrdiff_t)NG1 + c]     : 0.f;
  float u0 = (t0 >= 2) ? (float)base[-(ptrdiff_t)(2*NG1) + c] : 0.f;

  bf16* mbase = mixin + (size_t)(b * TSEQ + t0) * DMOD;
  #pragma unroll 4
  for (int t = 0; t < CLEN; ++t) {
    const bf16* row = base + (size_t)t * NG1;
    float u2 = (float)row[c];
    float gg = (float)row[DCONV + c];
    float conv = u0 * w0 + u1 * w1 + u2 * w2;
    mbase[(size_t)t * DMOD + c] = (bf16)(conv * (gg * sigmoidf_(gg)));
    u0 = u1; u1 = u2;
    float a, g;
    lru_step(row, c, coef, a, g);
    Hc = a * Hc + g;
    mbase[(size_t)t * DMOD + DCONV + c] = (bf16)Hc;
  }
}

// ---------------- launcher ----------------
extern "C" void kernel_launch(void* const* d_in, const int* in_sizes, int n_in,
                              void* d_out, int out_size, void* d_ws, size_t ws_size,
                              hipStream_t stream)
{
  const float* x         = (const float*)d_in[0];
  const float* vel_in    = (const float*)d_in[1];
  const float* pre_w     = (const float*)d_in[2];
  const float* conv_in_w = (const float*)d_in[3];
  const float* conv_dw   = (const float*)d_in[4];
  const float* gv        = (const float*)d_in[5];
  const float* gr        = (const float*)d_in[6];
  const float* gi        = (const float*)d_in[7];
  const float* lam       = (const float*)d_in[8];
  const float* out_w     = (const float*)d_in[9];
  const float* log_beta  = (const float*)d_in[10];
  const float* ffn_w     = (const float*)d_in[11];
  const float* w1        = (const float*)d_in[12];
  const float* w3        = (const float*)d_in[13];
  const float* w2        = (const float*)d_in[14];

  char* ws = (char*)d_ws;
  size_t off = 0;
  auto alloc = [&](size_t bytes) { void* p = ws + off; off += (bytes + 255) & ~(size_t)255; return p; };

  bf16*  WT_G1  = (bf16*)alloc((size_t)NG1 * DMOD * 2);
  bf16*  WT_OUT = (bf16*)alloc((size_t)DMOD * DMOD * 2);
  bf16*  WT_W13 = (bf16*)alloc((size_t)2 * DFFN * DMOD * 2);
  bf16*  WT_W2  = (bf16*)alloc((size_t)DMOD * DFFN * 2);
  float* CA     = (float*)alloc((size_t)BSZ * DGRIF * NCH * 4);
  float* CB     = (float*)alloc((size_t)BSZ * DGRIF * NCH * 4);
  bf16*  XN     = (bf16*)alloc((size_t)BT * DMOD * 2);
  bf16*  G1     = (bf16*)alloc((size_t)BT * NG1 * 2);
  bf16*  MIXIN  = (bf16*)alloc((size_t)BT * DMOD * 2);
  bf16*  H      = (bf16*)alloc((size_t)BT * DFFN * 2);
  bf16*  NORMED = (bf16*)alloc((size_t)BT * DMOD * 2);

  float* OUTX   = (float*)d_out;
  float* OUTV   = OUTX + (size_t)BT * DMOD;

  // prep: all weight transposes + pre-rmsnorm in one launch
  prep_kernel<<<6624 + BT, 256, 0, stream>>>(conv_in_w, gv, gr, gi, out_w, w1, w3, w2,
                                             WT_G1, WT_OUT, WT_W13, WT_W2,
                                             x, pre_w, XN);

  // GEMM1 (dbuf 128^2): [8192,768] @ [768,1920] -> G1 (bf16)
  gemm_w128d<<<(NG1/128) * (BT/128), 256, 0, stream>>>(XN, WT_G1, G1, BT, NG1, DMOD, NG1/128);

  // RG-LRU + fused conv -> MIXIN
  lru_pass1<<<(BSZ * NCH * DGRIF) / 256, 256, 0, stream>>>(G1, lam, CA, CB);
  lru_pass2<<<(BSZ * NCH * DGRIF) / 256, 256, 0, stream>>>(G1, lam, CA, CB, conv_dw, MIXIN);

  // GEMM2 (128x64 dbuf, momentum epilogue): OUTX = x + vel, OUTV = vel
  gemm_n64<0><<<(DMOD/64) * (BT/128), 256, 0, stream>>>(MIXIN, WT_OUT, OUTX, x, vel_in, OUTV,
                                                        log_beta, BT, DMOD, DMOD, DMOD/64);

  // ffn rmsnorm on x1
  rmsnorm_kernel<<<BT, 256, 0, stream>>>(OUTX, ffn_w, NORMED);

  // fused FFN up-proj + SwiGLU (256x128, 2D XCD chunking) -> H
  gemm_ffn13b<<<(BT/256) * (DFFN/64), 512, 0, stream>>>(NORMED, WT_W13, H, BT, DMOD);

  // down-proj (128x64 dbuf, accumulate): OUTX += H @ w2
  gemm_n64<1><<<(DMOD/64) * (BT/128), 256, 0, stream>>>(H, WT_W2, OUTX, nullptr, nullptr, nullptr,
                                                        nullptr, BT, DMOD, DFFN, DMOD/64);
}

// Round 14
// 245.749 us; speedup vs baseline: 1.0500x; 1.0500x over previous
//
#include <hip/hip_runtime.h>
#include <hip/hip_bf16.h>
#include <cstdint>

// ---------------- problem constants ----------------
#define BSZ   4
#define TSEQ  2048
#define DMOD  768
#define DCONV 384
#define DGRIF 384
#define DFFN  2048
#define BT    (BSZ*TSEQ)          // 8192
#define NG1   1920                // 2*DCONV + 3*DGRIF
#define EPS_  1e-6f

typedef __bf16 bf16;
typedef __bf16 bf16x8 __attribute__((ext_vector_type(8)));
typedef float  f32x4  __attribute__((ext_vector_type(4)));

__device__ __forceinline__ float sigmoidf_(float x) { return 1.f / (1.f + __expf(-x)); }

__device__ __forceinline__ void gload_lds16(const void* g, void* l) {
  __builtin_amdgcn_global_load_lds(
      (const __attribute__((address_space(1))) void*)(uintptr_t)g,
      (__attribute__((address_space(3))) void*)(uint32_t)(uintptr_t)l,
      16, 0, 0);
}

// bijective XCD swizzle: all GEMM grids are % 8 == 0
__device__ __forceinline__ int swz_wg() {
  const int nwg = gridDim.x;
  const int bid = blockIdx.x;
  const int cpx = nwg >> 3;
  return (bid & 7) * cpx + (bid >> 3);
}

// ---------------- prep: merged weight transposes + pre-rmsnorm (1 launch) ----------------
__global__ __launch_bounds__(256) void prep_kernel(
    const float* __restrict__ conv_in_w, const float* __restrict__ gv,
    const float* __restrict__ gr, const float* __restrict__ gi,
    const float* __restrict__ out_w, const float* __restrict__ w1,
    const float* __restrict__ w3, const float* __restrict__ w2,
    bf16* __restrict__ WT_G1, bf16* __restrict__ WT_OUT,
    bf16* __restrict__ WT_W13, bf16* __restrict__ WT_W2,
    const float* __restrict__ x, const float* __restrict__ pre_w,
    bf16* __restrict__ XN)
{
  __shared__ float tile[32][33];
  if (blockIdx.x >= 6624) {
    // ---- rmsnorm branch ----
    const int row = blockIdx.x - 6624;
    const int tid = threadIdx.x;
    const float* xr = x + (size_t)row * DMOD;
    float v0 = xr[tid], v1 = xr[tid + 256], v2 = xr[tid + 512];
    float s = v0*v0 + v1*v1 + v2*v2;
    #pragma unroll
    for (int o = 32; o > 0; o >>= 1) s += __shfl_down(s, o, 64);
    __shared__ float sbuf[4];
    if ((tid & 63) == 0) sbuf[tid >> 6] = s;
    __syncthreads();
    float tot = sbuf[0] + sbuf[1] + sbuf[2] + sbuf[3];
    float rms = rsqrtf(tot * (1.f / (float)DMOD) + EPS_);
    bf16* orow = XN + (size_t)row * DMOD;
    orow[tid]       = (bf16)(v0 * rms * pre_w[tid]);
    orow[tid + 256] = (bf16)(v1 * rms * pre_w[tid + 256]);
    orow[tid + 512] = (bf16)(v2 * rms * pre_w[tid + 512]);
    return;
  }
  // ---- transpose branch ----
  int t = blockIdx.x;
  const float* W; bf16* Wt; int R, C, mode = 0, half = 0;
  if      (t < 576)  {           W = conv_in_w; Wt = WT_G1;                        R = 768;  C = 768; }
  else if (t < 864)  { t -= 576;  W = gv;  Wt = WT_G1 + (size_t)768  * DMOD;       R = 768;  C = 384; }
  else if (t < 1152) { t -= 864;  W = gr;  Wt = WT_G1 + (size_t)1152 * DMOD;       R = 768;  C = 384; }
  else if (t < 1440) { t -= 1152; W = gi;  Wt = WT_G1 + (size_t)1536 * DMOD;       R = 768;  C = 384; }
  else if (t < 2016) { t -= 1440; W = out_w; Wt = WT_OUT;                          R = 768;  C = 768; }
  else if (t < 3552) { t -= 2016; W = w1;  Wt = WT_W13; mode = 1; half = 0;        R = 768;  C = 2048; }
  else if (t < 5088) { t -= 3552; W = w3;  Wt = WT_W13; mode = 1; half = 64;       R = 768;  C = 2048; }
  else               { t -= 5088; W = w2;  Wt = WT_W2;                             R = 2048; C = 768; }

  const int xt = C >> 5;
  const int tc = (t % xt) * 32, tr = (t / xt) * 32;
  const int lx = threadIdx.x & 31;
  const int ly = threadIdx.x >> 5;
  #pragma unroll
  for (int i = ly; i < 32; i += 8) {
    int r = tr + i, c = tc + lx;
    tile[i][lx] = (r < R && c < C) ? W[(size_t)r * C + c] : 0.f;
  }
  __syncthreads();
  #pragma unroll
  for (int i = ly; i < 32; i += 8) {
    int oc = tc + i;
    int orr = tr + lx;
    if (oc < C && orr < R) {
      int orow = (mode == 0) ? oc : ((oc >> 6) << 7) + half + (oc & 63);
      Wt[(size_t)orow * R + orr] = (bf16)tile[lx][i];
    }
  }
}

// ---------------- rmsnorm (x fp32 -> out bf16) ----------------
__global__ __launch_bounds__(256) void rmsnorm_kernel(
    const float* __restrict__ x, const float* __restrict__ w, bf16* __restrict__ out)
{
  __shared__ float sbuf[4];
  const int row = blockIdx.x;
  const int tid = threadIdx.x;
  const float* xr = x + (size_t)row * DMOD;
  float v0 = xr[tid], v1 = xr[tid + 256], v2 = xr[tid + 512];
  float s = v0*v0 + v1*v1 + v2*v2;
  #pragma unroll
  for (int o = 32; o > 0; o >>= 1) s += __shfl_down(s, o, 64);
  if ((tid & 63) == 0) sbuf[tid >> 6] = s;
  __syncthreads();
  float tot = sbuf[0] + sbuf[1] + sbuf[2] + sbuf[3];
  float rms = rsqrtf(tot * (1.f / (float)DMOD) + EPS_);
  bf16* orow = out + (size_t)row * DMOD;
  orow[tid]       = (bf16)(v0 * rms * w[tid]);
  orow[tid + 256] = (bf16)(v1 * rms * w[tid + 256]);
  orow[tid + 512] = (bf16)(v2 * rms * w[tid + 512]);
}

// ---------------- 128x128 GEMM, dbuf minimum-2-phase, T2-swizzled (GEMM1) ----------------
__global__ __launch_bounds__(256) void gemm_w128d(
    const bf16* __restrict__ A, const bf16* __restrict__ Bt, bf16* __restrict__ C,
    int M, int N, int K, int nx)
{
  __shared__ alignas(16) unsigned short As[2][128 * 64];   // 2 x 16 KB
  __shared__ alignas(16) unsigned short Bs[2][128 * 64];   // 2 x 16 KB

  const int wg = swz_wg();
  const int m0 = (wg / nx) * 128, n0 = (wg % nx) * 128;
  const int tid  = threadIdx.x;
  const int wave = tid >> 6;
  const int lane = tid & 63;
  const int wr = wave >> 1, wc = wave & 1;

  f32x4 acc[4][4] = {};
  const int srow = lane >> 3;
  const int scol = ((lane & 7) ^ srow) * 8;
  const int lr = lane & 15;
  const int lsw = lr & 7;
  const int lk4 = lane >> 4;

  auto stage = [&](int buf, int k0) {
    #pragma unroll
    for (int it = 0; it < 4; ++it) {
      const int chunk = wave * 4 + it;
      const int row = chunk * 8 + srow;
      gload_lds16(A  + (size_t)(m0 + row) * K + k0 + scol, (char*)As[buf] + chunk * 1024);
      gload_lds16(Bt + (size_t)(n0 + row) * K + k0 + scol, (char*)Bs[buf] + chunk * 1024);
    }
  };

  stage(0, 0);
  __syncthreads();

  int cur = 0;
  for (int k0 = 0; k0 < K; k0 += 64) {
    if (k0 + 64 < K) stage(cur ^ 1, k0 + 64);
    #pragma unroll
    for (int kk = 0; kk < 2; ++kk) {
      bf16x8 af[4], bfr[4];
      #pragma unroll
      for (int i = 0; i < 4; ++i)
        af[i] = *reinterpret_cast<const bf16x8*>(
            &As[cur][(wr*64 + i*16 + lr) * 64 + (((kk*4 + lk4) ^ lsw) * 8)]);
      #pragma unroll
      for (int i = 0; i < 4; ++i)
        bfr[i] = *reinterpret_cast<const bf16x8*>(
            &Bs[cur][(wc*64 + i*16 + lr) * 64 + (((kk*4 + lk4) ^ lsw) * 8)]);
      #pragma unroll
      for (int mi = 0; mi < 4; ++mi)
        #pragma unroll
        for (int ni = 0; ni < 4; ++ni)
          acc[mi][ni] = __builtin_amdgcn_mfma_f32_16x16x32_bf16(af[mi], bfr[ni], acc[mi][ni], 0, 0, 0);
    }
    __syncthreads();
    cur ^= 1;
  }

  #pragma unroll
  for (int mi = 0; mi < 4; ++mi)
    #pragma unroll
    for (int ni = 0; ni < 4; ++ni)
      #pragma unroll
      for (int reg = 0; reg < 4; ++reg) {
        const int r = m0 + wr*64 + mi*16 + lk4 * 4 + reg;
        const int c = n0 + wc*64 + ni*16 + lr;
        C[(size_t)r * N + c] = (bf16)acc[mi][ni][reg];
      }
}

// ---------------- fused FFN GEMM: 128x128 dbuf + 2D XCD chunking ----------------
// Grid 2048 = 64 m-tiles x 32 n-blocks. XCD k = (m-group k&3: 16 m-tiles) x (n-half k>>2: 16 n-blocks).
// Within XCD: n-inner (A-tile L2-hot across 16 blocks; 3.1 MB B-half L2-resident).
// Bt rows (j*128+0..63)=w1 cols j*64.., rows (j*128+64..127)=w3; block covers j=bx.
__global__ __launch_bounds__(256) void gemm_ffn13d(
    const bf16* __restrict__ A, const bf16* __restrict__ Bt, bf16* __restrict__ H,
    int M, int K)
{
  __shared__ alignas(16) unsigned short As[2][128 * 64];
  __shared__ alignas(16) unsigned short Bs[2][128 * 64];
  bf16* comb = reinterpret_cast<bf16*>(As);   // 16 KB, dead after K-loop

  const int xcd = blockIdx.x & 7;
  const int w   = blockIdx.x >> 3;            // 0..255
  const int mt  = (xcd & 3) * 16 + (w >> 4);  // m-tile 0..63
  const int bx  = (xcd >> 2) * 16 + (w & 15); // n-block 0..31
  const int m0 = mt * 128;
  const int n0 = bx * 128;
  const int tid  = threadIdx.x;
  const int wave = tid >> 6;
  const int lane = tid & 63;
  const int wr = wave >> 1, wc = wave & 1;

  f32x4 acc[4][4] = {};
  const int srow = lane >> 3;
  const int scol = ((lane & 7) ^ srow) * 8;
  const int lr = lane & 15;
  const int lsw = lr & 7;
  const int lk4 = lane >> 4;

  auto stage = [&](int buf, int k0) {
    #pragma unroll
    for (int it = 0; it < 4; ++it) {
      const int chunk = wave * 4 + it;
      const int row = chunk * 8 + srow;
      gload_lds16(A  + (size_t)(m0 + row) * K + k0 + scol, (char*)As[buf] + chunk * 1024);
      gload_lds16(Bt + (size_t)(n0 + row) * K + k0 + scol, (char*)Bs[buf] + chunk * 1024);
    }
  };

  stage(0, 0);
  __syncthreads();

  int cur = 0;
  for (int k0 = 0; k0 < K; k0 += 64) {
    if (k0 + 64 < K) stage(cur ^ 1, k0 + 64);
    #pragma unroll
    for (int kk = 0; kk < 2; ++kk) {
      bf16x8 af[4], bfr[4];
      #pragma unroll
      for (int i = 0; i < 4; ++i)
        af[i] = *reinterpret_cast<const bf16x8*>(
            &As[cur][(wr*64 + i*16 + lr) * 64 + (((kk*4 + lk4) ^ lsw) * 8)]);
      #pragma unroll
      for (int i = 0; i < 4; ++i)
        bfr[i] = *reinterpret_cast<const bf16x8*>(
            &Bs[cur][(wc*64 + i*16 + lr) * 64 + (((kk*4 + lk4) ^ lsw) * 8)]);
      #pragma unroll
      for (int mi = 0; mi < 4; ++mi)
        #pragma unroll
        for (int ni = 0; ni < 4; ++ni)
          acc[mi][ni] = __builtin_amdgcn_mfma_f32_16x16x32_bf16(af[mi], bfr[ni], acc[mi][ni], 0, 0, 0);
    }
    __syncthreads();
    cur ^= 1;
  }

  // p1/p3 exchange: wc==1 (p3) stashes through comb; wc==0 (p1) emits gated H
  if (wc == 1) {
    #pragma unroll
    for (int mi = 0; mi < 4; ++mi)
      #pragma unroll
      for (int ni = 0; ni < 4; ++ni)
        #pragma unroll
        for (int reg = 0; reg < 4; ++reg) {
          const int row = wr*64 + mi*16 + lk4 * 4 + reg;
          const int col = ni*16 + lr;
          comb[row * 64 + col] = (bf16)acc[mi][ni][reg];
        }
  }
  __syncthreads();
  if (wc == 0) {
    #pragma unroll
    for (int mi = 0; mi < 4; ++mi)
      #pragma unroll
      for (int ni = 0; ni < 4; ++ni)
        #pragma unroll
        for (int reg = 0; reg < 4; ++reg) {
          const int row = wr*64 + mi*16 + lk4 * 4 + reg;
          const int col = ni*16 + lr;
          float p3 = (float)comb[row * 64 + col];
          float p1 = acc[mi][ni][reg];
          H[(size_t)(m0 + row) * DFFN + bx * 64 + col] = (bf16)(p1 * sigmoidf_(p1) * p3);
        }
  }
}

// ---------------- narrow GEMM: 128x64 tile, dbuf minimum-2-phase ----------------
// EPI 0: momentum epilogue.  EPI 1: Cf += acc.
template <int EPI>
__global__ __launch_bounds__(256) void gemm_n64(
    const bf16* __restrict__ A, const bf16* __restrict__ Bt, float* __restrict__ C,
    const float* __restrict__ xin, const float* __restrict__ vin,
    float* __restrict__ outv, const float* __restrict__ log_beta,
    int M, int N, int K, int nx)
{
  __shared__ alignas(16) unsigned short As[2][128 * 64];   // 2 x 16 KB
  __shared__ alignas(16) unsigned short Bs[2][64 * 64];    // 2 x  8 KB

  const int wg = swz_wg();
  const int m0 = (wg / nx) * 128, n0 = (wg % nx) * 64;
  const int tid  = threadIdx.x;
  const int wave = tid >> 6;
  const int lane = tid & 63;
  const int wr = wave >> 1, wc = wave & 1;

  f32x4 acc[4][2] = {};
  const int srow = lane >> 3;
  const int scol = ((lane & 7) ^ srow) * 8;
  const int lr = lane & 15;
  const int lsw = lr & 7;
  const int lk4 = lane >> 4;

  auto stage = [&](int buf, int k0) {
    #pragma unroll
    for (int it = 0; it < 6; ++it) {
      const int chunk = wave * 6 + it;
      if (chunk < 16) {
        const int row = chunk * 8 + srow;
        gload_lds16(A + (size_t)(m0 + row) * K + k0 + scol,
                    (char*)As[buf] + chunk * 1024);
      } else {
        const int row = (chunk - 16) * 8 + srow;
        gload_lds16(Bt + (size_t)(n0 + row) * K + k0 + scol,
                    (char*)Bs[buf] + (chunk - 16) * 1024);
      }
    }
  };

  stage(0, 0);
  __syncthreads();

  int cur = 0;
  for (int k0 = 0; k0 < K; k0 += 64) {
    if (k0 + 64 < K) stage(cur ^ 1, k0 + 64);
    #pragma unroll
    for (int kk = 0; kk < 2; ++kk) {
      bf16x8 af[4], bfr[2];
      #pragma unroll
      for (int i = 0; i < 4; ++i)
        af[i] = *reinterpret_cast<const bf16x8*>(
            &As[cur][(wr*64 + i*16 + lr) * 64 + (((kk*4 + lk4) ^ lsw) * 8)]);
      #pragma unroll
      for (int i = 0; i < 2; ++i)
        bfr[i] = *reinterpret_cast<const bf16x8*>(
            &Bs[cur][(wc*32 + i*16 + lr) * 64 + (((kk*4 + lk4) ^ lsw) * 8)]);
      #pragma unroll
      for (int mi = 0; mi < 4; ++mi)
        #pragma unroll
        for (int ni = 0; ni < 2; ++ni)
          acc[mi][ni] = __builtin_amdgcn_mfma_f32_16x16x32_bf16(af[mi], bfr[ni], acc[mi][ni], 0, 0, 0);
    }
    __syncthreads();
    cur ^= 1;
  }

  const float beta = (EPI == 0) ? sigmoidf_(log_beta[0]) : 0.f;
  #pragma unroll
  for (int mi = 0; mi < 4; ++mi)
    #pragma unroll
    for (int ni = 0; ni < 2; ++ni)
      #pragma unroll
      for (int reg = 0; reg < 4; ++reg) {
        const int r = m0 + wr*64 + mi*16 + lk4 * 4 + reg;
        const int c = n0 + wc*32 + ni*16 + lr;
        const size_t off = (size_t)r * N + c;
        float v = acc[mi][ni][reg];
        if (EPI == 0) {
          float vel = beta * vin[off] + v;
          float x1  = xin[off] + vel;
          outv[off] = vel;
          C[off] = x1;
        } else {
          C[off] += v;
        }
      }
}

// ---------------- RG-LRU 2-pass chunked scan + fused conv ----------------
#define NCH  32
#define CLEN 64

__device__ __forceinline__ void lru_step(const bf16* row, int c, float coef,
                                         float& a, float& g)
{
  float v  = (float)row[2*DCONV + c];
  float r  = sigmoidf_((float)row[2*DCONV + DGRIF + c]);
  float is = sigmoidf_((float)row[2*DCONV + 2*DGRIF + c]);
  float la = coef * r;
  a = __expf(la);
  g = sqrtf(fmaxf(1.f - __expf(2.f * la), EPS_)) * (is * v);
}

__global__ __launch_bounds__(256) void lru_pass1(
    const bf16* __restrict__ g1, const float* __restrict__ lam,
    float* __restrict__ cA, float* __restrict__ cB)
{
  const int idx = blockIdx.x * 256 + threadIdx.x;
  const int c = idx % DGRIF;
  const int rest = idx / DGRIF;
  const int j = rest & (NCH - 1);
  const int b = rest / NCH;
  const float coef = -8.f * log1pf(__expf(lam[c]));
  const bf16* base = g1 + (size_t)(b * TSEQ + j * CLEN) * NG1;
  float A = 1.f, Bv = 0.f;
  #pragma unroll 4
  for (int t = 0; t < CLEN; ++t) {
    float a, g;
    lru_step(base + (size_t)t * NG1, c, coef, a, g);
    A *= a;
    Bv = a * Bv + g;
  }
  cA[((size_t)b * DGRIF + c) * NCH + j] = A;
  cB[((size_t)b * DGRIF + c) * NCH + j] = Bv;
}

__global__ __launch_bounds__(256) void lru_pass2(
    const bf16* __restrict__ g1, const float* __restrict__ lam,
    const float* __restrict__ cA, const float* __restrict__ cB,
    const float* __restrict__ dw, bf16* __restrict__ mixin)
{
  const int idx = blockIdx.x * 256 + threadIdx.x;
  const int c = idx % DGRIF;
  const int rest = idx / DGRIF;
  const int j = rest & (NCH - 1);
  const int b = rest / NCH;
  const float coef = -8.f * log1pf(__expf(lam[c]));
  float Hc = 0.f;
  const float* pa = cA + ((size_t)b * DGRIF + c) * NCH;
  const float* pb = cB + ((size_t)b * DGRIF + c) * NCH;
  for (int k = 0; k < j; ++k) Hc = pa[k] * Hc + pb[k];

  const int t0 = j * CLEN;
  const bf16* base = g1 + (size_t)(b * TSEQ + t0) * NG1;
  const float w0 = dw[c*3], w1 = dw[c*3 + 1], w2 = dw[c*3 + 2];
  float u1 = (t0 >= 1) ? (float)base[-(ptrdiff_t)NG1 + c]     : 0.f;
  float u0 = (t0 >= 2) ? (float)base[-(ptrdiff_t)(2*NG1) + c] : 0.f;

  bf16* mbase = mixin + (size_t)(b * TSEQ + t0) * DMOD;
  #pragma unroll 4
  for (int t = 0; t < CLEN; ++t) {
    const bf16* row = base + (size_t)t * NG1;
    float u2 = (float)row[c];
    float gg = (float)row[DCONV + c];
    float conv = u0 * w0 + u1 * w1 + u2 * w2;
    mbase[(size_t)t * DMOD + c] = (bf16)(conv * (gg * sigmoidf_(gg)));
    u0 = u1; u1 = u2;
    float a, g;
    lru_step(row, c, coef, a, g);
    Hc = a * Hc + g;
    mbase[(size_t)t * DMOD + DCONV + c] = (bf16)Hc;
  }
}

// ---------------- launcher ----------------
extern "C" void kernel_launch(void* const* d_in, const int* in_sizes, int n_in,
                              void* d_out, int out_size, void* d_ws, size_t ws_size,
                              hipStream_t stream)
{
  const float* x         = (const float*)d_in[0];
  const float* vel_in    = (const float*)d_in[1];
  const float* pre_w     = (const float*)d_in[2];
  const float* conv_in_w = (const float*)d_in[3];
  const float* conv_dw   = (const float*)d_in[4];
  const float* gv        = (const float*)d_in[5];
  const float* gr        = (const float*)d_in[6];
  const float* gi        = (const float*)d_in[7];
  const float* lam       = (const float*)d_in[8];
  const float* out_w     = (const float*)d_in[9];
  const float* log_beta  = (const float*)d_in[10];
  const float* ffn_w     = (const float*)d_in[11];
  const float* w1        = (const float*)d_in[12];
  const float* w3        = (const float*)d_in[13];
  const float* w2        = (const float*)d_in[14];

  char* ws = (char*)d_ws;
  size_t off = 0;
  auto alloc = [&](size_t bytes) { void* p = ws + off; off += (bytes + 255) & ~(size_t)255; return p; };

  bf16*  WT_G1  = (bf16*)alloc((size_t)NG1 * DMOD * 2);
  bf16*  WT_OUT = (bf16*)alloc((size_t)DMOD * DMOD * 2);
  bf16*  WT_W13 = (bf16*)alloc((size_t)2 * DFFN * DMOD * 2);
  bf16*  WT_W2  = (bf16*)alloc((size_t)DMOD * DFFN * 2);
  float* CA     = (float*)alloc((size_t)BSZ * DGRIF * NCH * 4);
  float* CB     = (float*)alloc((size_t)BSZ * DGRIF * NCH * 4);
  bf16*  XN     = (bf16*)alloc((size_t)BT * DMOD * 2);
  bf16*  G1     = (bf16*)alloc((size_t)BT * NG1 * 2);
  bf16*  MIXIN  = (bf16*)alloc((size_t)BT * DMOD * 2);
  bf16*  H      = (bf16*)alloc((size_t)BT * DFFN * 2);
  bf16*  NORMED = (bf16*)alloc((size_t)BT * DMOD * 2);

  float* OUTX   = (float*)d_out;
  float* OUTV   = OUTX + (size_t)BT * DMOD;

  // prep: all weight transposes + pre-rmsnorm in one launch
  prep_kernel<<<6624 + BT, 256, 0, stream>>>(conv_in_w, gv, gr, gi, out_w, w1, w3, w2,
                                             WT_G1, WT_OUT, WT_W13, WT_W2,
                                             x, pre_w, XN);

  // GEMM1 (dbuf 128^2): [8192,768] @ [768,1920] -> G1 (bf16)
  gemm_w128d<<<(NG1/128) * (BT/128), 256, 0, stream>>>(XN, WT_G1, G1, BT, NG1, DMOD, NG1/128);

  // RG-LRU + fused conv -> MIXIN
  lru_pass1<<<(BSZ * NCH * DGRIF) / 256, 256, 0, stream>>>(G1, lam, CA, CB);
  lru_pass2<<<(BSZ * NCH * DGRIF) / 256, 256, 0, stream>>>(G1, lam, CA, CB, conv_dw, MIXIN);

  // GEMM2 (128x64 dbuf, momentum epilogue): OUTX = x + vel, OUTV = vel
  gemm_n64<0><<<(DMOD/64) * (BT/128), 256, 0, stream>>>(MIXIN, WT_OUT, OUTX, x, vel_in, OUTV,
                                                        log_beta, BT, DMOD, DMOD, DMOD/64);

  // ffn rmsnorm on x1
  rmsnorm_kernel<<<BT, 256, 0, stream>>>(OUTX, ffn_w, NORMED);

  // fused FFN up-proj + SwiGLU (dbuf 128^2 + 2D XCD chunking) -> H
  gemm_ffn13d<<<(BT/128) * (DFFN/64), 256, 0, stream>>>(NORMED, WT_W13, H, BT, DMOD);

  // down-proj (128x64 dbuf, accumulate): OUTX += H @ w2
  gemm_n64<1><<<(DMOD/64) * (BT/128), 256, 0, stream>>>(H, WT_W2, OUTX, nullptr, nullptr, nullptr,
                                                        nullptr, BT, DMOD, DFFN, DMOD/64);
}